// Round 14
// baseline (282.242 us; speedup 1.0000x reference)
//
#include <hip/hip_runtime.h>

#define N_NODES 50000
#define NIN 512
#define NH 96
#define NL 32
#define NH2 64

#define SCAN_BLK 49
#define NB 1563          // coarse buckets of 32 nodes

typedef __attribute__((ext_vector_type(8))) short short8v;   // 8 bf16 (4 VGPR)
typedef __attribute__((ext_vector_type(4))) float f32x4;

__device__ __forceinline__ unsigned short f2bf(float f) {    // RNE f32->bf16
    unsigned u = __float_as_uint(f);
    u = (u + 0x7FFFu + ((u >> 16) & 1u)) >> 16;
    return (unsigned short)u;
}
__device__ __forceinline__ float bf2f(unsigned short h) {
    return __uint_as_float((unsigned)h << 16);
}

// fused: WbT = W1^T bf16; W2T = [Wmu|Wls]^T bf16; degi = 0; ccur = 0
__global__ __launch_bounds__(256) void k_prep(const float* __restrict__ W1,
                                              const float* __restrict__ Wmu,
                                              const float* __restrict__ Wls,
                                              unsigned short* __restrict__ WbT,
                                              unsigned short* __restrict__ W2T,
                                              int* __restrict__ degi,
                                              int* __restrict__ ccur) {
    int idx = blockIdx.x * 256 + threadIdx.x;
    if (idx < NH * NIN) {
        int n = idx >> 9, k = idx & 511;
        WbT[idx] = f2bf(W1[(size_t)k * NH + n]);
    } else if (idx < NH * NIN + NH2 * NH) {
        int j = idx - NH * NIN;
        int n = j / NH, k = j - n * NH;
        float v = (n < NL) ? Wmu[k * NL + n] : Wls[k * NL + (n - NL)];
        W2T[j] = f2bf(v);
    }
    if (idx < N_NODES) degi[idx] = 0;
    if (idx < NB) ccur[idx] = 0;
}

__global__ void k_degi(const int* __restrict__ dst, int* __restrict__ degi, int E) {
    int i = blockIdx.x * blockDim.x + threadIdx.x;
    if (i < E) atomicAdd(&degi[dst[i]], 1);
}

__global__ __launch_bounds__(256) void k_scan1(const int* __restrict__ degi,
                                               int* __restrict__ bsum) {
    __shared__ int red[256];
    int t = threadIdx.x;
    int q = blockIdx.x * 256 + t;
    int s = 0;
    if (q * 4 + 3 < N_NODES) {
        int4 v = reinterpret_cast<const int4*>(degi)[q];
        s = v.x + v.y + v.z + v.w;
    } else {
        for (int j = q * 4; j < min(q * 4 + 4, N_NODES); j++) s += degi[j];
    }
    red[t] = s;
    __syncthreads();
    for (int off = 128; off > 0; off >>= 1) {
        if (t < off) red[t] += red[t + off];
        __syncthreads();
    }
    if (t == 0) bsum[blockIdx.x] = red[0];
}

__global__ __launch_bounds__(64) void k_scan2(const int* __restrict__ bsum,
                                              int* __restrict__ boff) {
    int lane = threadIdx.x;
    int v = (lane < SCAN_BLK) ? bsum[lane] : 0;
    int orig = v;
    for (int off = 1; off < 64; off <<= 1) {
        int w = __shfl_up(v, off, 64);
        if (lane >= off) v += w;
    }
    if (lane < SCAN_BLK) boff[lane] = v - orig;
}

__global__ __launch_bounds__(256) void k_scan3(const int* __restrict__ degi,
                                               const int* __restrict__ boff,
                                               int* __restrict__ rowoff,
                                               float* __restrict__ dis) {
    __shared__ int sums[256];
    int t = threadIdx.x;
    int q = blockIdx.x * 256 + t;
    int d[4] = {0, 0, 0, 0};
    if (q * 4 + 3 < N_NODES) {
        int4 v = reinterpret_cast<const int4*>(degi)[q];
        d[0] = v.x; d[1] = v.y; d[2] = v.z; d[3] = v.w;
    } else {
        for (int j = 0; j < 4; j++)
            if (q * 4 + j < N_NODES) d[j] = degi[q * 4 + j];
    }
    int tsum = d[0] + d[1] + d[2] + d[3];
    sums[t] = tsum;
    __syncthreads();
    for (int off = 1; off < 256; off <<= 1) {
        int v = (t >= off) ? sums[t - off] : 0;
        __syncthreads();
        sums[t] += v;
        __syncthreads();
    }
    int run = boff[blockIdx.x] + sums[t] - tsum;
#pragma unroll
    for (int j = 0; j < 4; j++) {
        int i = q * 4 + j;
        if (i < N_NODES) {
            rowoff[i] = run;
            dis[i] = rsqrtf((float)d[j] + 1.0f);
            run += d[j];
            if (i == N_NODES - 1) rowoff[N_NODES] = run;
        }
    }
}

// coarse bucket pass: append (src,dst) into node-range-32 regions.
// Region base = rowoff[b*32] (free from the node scan); appends are sequential
// within a region -> dense cache-line fill (vs 4B random scatter = 55MB writes).
__global__ void k_coarse(const int* __restrict__ src, const int* __restrict__ dst,
                         const int* __restrict__ rowoff, int* __restrict__ ccur,
                         uint2* __restrict__ cpair, int E) {
    int e = blockIdx.x * blockDim.x + threadIdx.x;
    if (e >= E) return;
    int s = src[e], d = dst[e];
    int b = d >> 5;
    int pos = rowoff[b << 5] + atomicAdd(&ccur[b], 1);
    cpair[pos] = make_uint2((unsigned)s, (unsigned)d);
}

// fine pass: one block per coarse bucket; LDS per-node counters (no global
// atomics); esrc writes land densely in the bucket's ~2KB final window.
__global__ __launch_bounds__(256) void k_fine(const uint2* __restrict__ cpair,
                                              const int* __restrict__ rowoff,
                                              int* __restrict__ esrc) {
    __shared__ int lcur[32];
    int bb = blockIdx.x;
    int n0 = bb << 5;
    int t = threadIdx.x;
    if (t < 32) lcur[t] = 0;
    __syncthreads();
    int p0 = rowoff[n0];
    int p1 = rowoff[min(n0 + 32, N_NODES)];
    for (int p = p0 + t; p < p1; p += 256) {
        uint2 ed = cpair[p];
        int d = (int)ed.y;
        int pos = rowoff[d] + atomicAdd(&lcur[d - n0], 1);
        esrc[pos] = (int)ed.x;
    }
}

// h' = (x @ W1) * dis[row], bf16 MFMA 16x16x32 (r12 config: no prefetch).
// BM=128 (4 waves x 32 rows), BK=64, 8 K-tiles; LDS rows 128B, slot ^= (row&7).
#define GBM 128
__global__ __launch_bounds__(256, 2) void k_gemm1(const float* __restrict__ x,
                                                  const unsigned short* __restrict__ WbT,
                                                  const float* __restrict__ dis,
                                                  unsigned short* __restrict__ hb, int M) {
    __shared__ __align__(16) char lA[128 * 128];   // 16 KB
    __shared__ __align__(16) char lB[96 * 128];    // 12 KB
    int tid = threadIdx.x;
    int lane = tid & 63, w = tid >> 6;
    int l15 = lane & 15, hi = lane >> 4;
    int m0 = blockIdx.x * GBM;

    f32x4 acc[2][6];
#pragma unroll
    for (int rt = 0; rt < 2; ++rt)
#pragma unroll
        for (int nt = 0; nt < 6; ++nt)
#pragma unroll
            for (int i = 0; i < 4; ++i) acc[rt][nt][i] = 0.f;

    int key = l15 & 7;
    int arow0 = (w * 32 + l15) * 128;
    int arow1 = (w * 32 + 16 + l15) * 128;

    for (int kt = 0; kt < 8; ++kt) {
        __syncthreads();
#pragma unroll
        for (int i = 0; i < 4; ++i) {
            int s = i * 256 + tid;
            int r = s >> 3, sl = s & 7;
            const float* p = x + (size_t)min(m0 + r, M - 1) * NIN + kt * 64 + sl * 8;
            float4 a0 = *reinterpret_cast<const float4*>(p);
            float4 a1 = *reinterpret_cast<const float4*>(p + 4);
            uint4 pk;
            pk.x = (unsigned)f2bf(a0.x) | ((unsigned)f2bf(a0.y) << 16);
            pk.y = (unsigned)f2bf(a0.z) | ((unsigned)f2bf(a0.w) << 16);
            pk.z = (unsigned)f2bf(a1.x) | ((unsigned)f2bf(a1.y) << 16);
            pk.w = (unsigned)f2bf(a1.z) | ((unsigned)f2bf(a1.w) << 16);
            *reinterpret_cast<uint4*>(lA + r * 128 + ((sl ^ (r & 7)) << 4)) = pk;
        }
#pragma unroll
        for (int i = 0; i < 3; ++i) {
            int s = i * 256 + tid;
            int n = s >> 3, sl = s & 7;
            uint4 bv = *reinterpret_cast<const uint4*>(WbT + (size_t)n * NIN + kt * 64 + sl * 8);
            *reinterpret_cast<uint4*>(lB + n * 128 + ((sl ^ (n & 7)) << 4)) = bv;
        }
        __syncthreads();

#pragma unroll
        for (int kc = 0; kc < 2; ++kc) {
            int off = (((kc * 4 + hi) ^ key) << 4);
            short8v a0 = *reinterpret_cast<const short8v*>(lA + arow0 + off);
            short8v a1 = *reinterpret_cast<const short8v*>(lA + arow1 + off);
#pragma unroll
            for (int nt = 0; nt < 6; ++nt) {
                short8v bv = *reinterpret_cast<const short8v*>(lB + (nt * 16 + l15) * 128 + off);
                acc[0][nt] = __builtin_amdgcn_mfma_f32_16x16x32_bf16(a0, bv, acc[0][nt], 0, 0, 0);
                acc[1][nt] = __builtin_amdgcn_mfma_f32_16x16x32_bf16(a1, bv, acc[1][nt], 0, 0, 0);
            }
        }
    }

#pragma unroll
    for (int rt = 0; rt < 2; ++rt) {
        int rbase = m0 + w * 32 + rt * 16 + hi * 4;
#pragma unroll
        for (int r = 0; r < 4; ++r) {
            int orow = rbase + r;
            if (orow < M) {
                float dv = dis[orow];
                unsigned short* op = hb + (size_t)orow * NH + l15;
#pragma unroll
                for (int nt = 0; nt < 6; ++nt) op[nt * 16] = f2bf(acc[rt][nt][r] * dv);
            }
        }
    }
}

// gather layer 1 (bf16 rows, 192B): hid = relu((sum h'[s] + h'[i]) * dis + b1)
__global__ __launch_bounds__(256) void k_gather1(const ushort4* __restrict__ hb4,
                                                 const int* __restrict__ rowoff,
                                                 const int* __restrict__ esrc,
                                                 const float* __restrict__ dis,
                                                 const float* __restrict__ b1,
                                                 ushort4* __restrict__ hid4) {
    int tid = threadIdx.x;
    int node = blockIdx.x * 8 + (tid >> 5);
    int c = tid & 31;
    if (node >= N_NODES) return;
    int p0 = rowoff[node], p1 = rowoff[node + 1];
    bool act = (c < 24);
    float ax = 0.f, ay = 0.f, az = 0.f, aw = 0.f;
    for (int pb = p0; pb < p1; pb += 32) {
        int nb = min(32, p1 - pb);
        int sv = (c < nb) ? esrc[pb + c] : 0;
#pragma unroll 4
        for (int j = 0; j < nb; j++) {
            int s = __shfl(sv, j, 32);
            if (act) {
                ushort4 v = hb4[(size_t)s * 24 + c];
                ax += bf2f(v.x); ay += bf2f(v.y); az += bf2f(v.z); aw += bf2f(v.w);
            }
        }
    }
    if (act) {
        float dv = dis[node];
        ushort4 hv = hb4[(size_t)node * 24 + c];
        float4 bv = reinterpret_cast<const float4*>(b1)[c];
        ushort4 o;
        o.x = f2bf(fmaxf((ax + bf2f(hv.x)) * dv + bv.x, 0.f));
        o.y = f2bf(fmaxf((ay + bf2f(hv.y)) * dv + bv.y, 0.f));
        o.z = f2bf(fmaxf((az + bf2f(hv.z)) * dv + bv.z, 0.f));
        o.w = f2bf(fmaxf((aw + bf2f(hv.w)) * dv + bv.w, 0.f));
        hid4[(size_t)node * 24 + c] = o;
    }
}

// h23' = (hid @ W2) * dis[row], bf16 MFMA, LDS-free (W2T 12KB L1-hot)
#define GBM2 64
__global__ __launch_bounds__(256) void k_gemm2(const unsigned short* __restrict__ hid,
                                               const unsigned short* __restrict__ W2T,
                                               const float* __restrict__ dis,
                                               unsigned short* __restrict__ h23, int M) {
    int tid = threadIdx.x;
    int lane = tid & 63, w = tid >> 6;
    int l15 = lane & 15, hi = lane >> 4;
    int m0 = blockIdx.x * GBM2;
    int row = m0 + w * 16 + l15;
    const unsigned short* ap = hid + (size_t)min(row, M - 1) * NH + hi * 8;
    const unsigned short* bp = W2T + (size_t)l15 * NH + hi * 8;

    f32x4 acc[4];
#pragma unroll
    for (int nt = 0; nt < 4; ++nt)
#pragma unroll
        for (int i = 0; i < 4; ++i) acc[nt][i] = 0.f;

#pragma unroll
    for (int kc = 0; kc < 3; ++kc) {
        short8v av = *reinterpret_cast<const short8v*>(ap + kc * 32);
#pragma unroll
        for (int nt = 0; nt < 4; ++nt) {
            short8v bv = *reinterpret_cast<const short8v*>(bp + nt * 16 * NH + kc * 32);
            acc[nt] = __builtin_amdgcn_mfma_f32_16x16x32_bf16(av, bv, acc[nt], 0, 0, 0);
        }
    }

    int rbase = m0 + w * 16 + hi * 4;
#pragma unroll
    for (int r = 0; r < 4; ++r) {
        int orow = rbase + r;
        if (orow < M) {
            float dv = dis[orow];
            unsigned short* op = h23 + (size_t)orow * NH2 + l15;
#pragma unroll
            for (int nt = 0; nt < 4; ++nt) op[nt * 16] = f2bf(acc[nt][r] * dv);
        }
    }
}

// gather layer 2 (bf16 rows, 128B): out = (sum h23'[s] + h23'[i]) * dis + bias
__global__ __launch_bounds__(256) void k_gather2(const ushort4* __restrict__ hb4,
                                                 const int* __restrict__ rowoff,
                                                 const int* __restrict__ esrc,
                                                 const float* __restrict__ dis,
                                                 const float* __restrict__ bmu,
                                                 const float* __restrict__ bls,
                                                 float4* __restrict__ out4) {
    int tid = threadIdx.x;
    int node = blockIdx.x * 16 + (tid >> 4);
    int c = tid & 15;
    if (node >= N_NODES) return;
    int p0 = rowoff[node], p1 = rowoff[node + 1];
    float ax = 0.f, ay = 0.f, az = 0.f, aw = 0.f;
    for (int pb = p0; pb < p1; pb += 16) {
        int nb = min(16, p1 - pb);
        int sv = (c < nb) ? esrc[pb + c] : 0;
#pragma unroll 4
        for (int j = 0; j < nb; j++) {
            int s = __shfl(sv, j, 16);
            ushort4 v = hb4[(size_t)s * 16 + c];
            ax += bf2f(v.x); ay += bf2f(v.y); az += bf2f(v.z); aw += bf2f(v.w);
        }
    }
    float dv = dis[node];
    ushort4 hv = hb4[(size_t)node * 16 + c];
    float4 bv = (c < 8) ? reinterpret_cast<const float4*>(bmu)[c]
                        : reinterpret_cast<const float4*>(bls)[c - 8];
    float4 o;
    o.x = (ax + bf2f(hv.x)) * dv + bv.x;
    o.y = (ay + bf2f(hv.y)) * dv + bv.y;
    o.z = (az + bf2f(hv.z)) * dv + bv.z;
    o.w = (aw + bf2f(hv.w)) * dv + bv.w;
    if (c < 8) out4[(size_t)node * 8 + c] = o;
    else       out4[(size_t)N_NODES * 8 + (size_t)node * 8 + (c - 8)] = o;
}

extern "C" void kernel_launch(void* const* d_in, const int* in_sizes, int n_in,
                              void* d_out, int out_size, void* d_ws, size_t ws_size,
                              hipStream_t stream) {
    const float* x   = (const float*)d_in[0];
    const float* W1  = (const float*)d_in[1];
    const float* b1  = (const float*)d_in[2];
    const float* Wmu = (const float*)d_in[3];
    const float* bmu = (const float*)d_in[4];
    const float* Wls = (const float*)d_in[5];
    const float* bls = (const float*)d_in[6];
    const int*   ei  = (const int*)d_in[7];
    int E = in_sizes[7] / 2;
    const int* src  = ei;
    const int* dstp = ei + E;

    char* w = (char*)d_ws;
    int* degi    = (int*)w;            w += (size_t)N_NODES * 4;
    int* rowoff  = (int*)w;            w += ((size_t)N_NODES + 4) * 4;
    float* dis   = (float*)w;          w += (size_t)N_NODES * 4;
    int* bsum    = (int*)w;            w += 64 * 4;
    int* boff    = (int*)w;            w += 64 * 4;
    int* ccur    = (int*)w;            w += ((size_t)NB + 5) * 4;
    int* esrc    = (int*)w;            w += (size_t)E * 4;
    uint2* cpair = (uint2*)w;          w += (size_t)E * 8;
    unsigned short* WbT  = (unsigned short*)w;  w += (size_t)NH * NIN * 2;
    unsigned short* W2T  = (unsigned short*)w;  w += (size_t)NH2 * NH * 2;
    unsigned short* hbuf = (unsigned short*)w;  w += (size_t)N_NODES * NH * 2;
    unsigned short* hid  = (unsigned short*)w;  w += (size_t)N_NODES * NH * 2;
    unsigned short* h23  = (unsigned short*)w;  w += (size_t)N_NODES * NH2 * 2;

    int prep_n = NH * NIN + NH2 * NH;
    k_prep<<<(prep_n + 255) / 256, 256, 0, stream>>>(W1, Wmu, Wls, WbT, W2T, degi, ccur);

    k_degi<<<(E + 255) / 256, 256, 0, stream>>>(dstp, degi, E);
    k_scan1<<<SCAN_BLK, 256, 0, stream>>>(degi, bsum);
    k_scan2<<<1, 64, 0, stream>>>(bsum, boff);
    k_scan3<<<SCAN_BLK, 256, 0, stream>>>(degi, boff, rowoff, dis);

    k_coarse<<<(E + 255) / 256, 256, 0, stream>>>(src, dstp, rowoff, ccur, cpair, E);
    k_fine<<<NB, 256, 0, stream>>>(cpair, rowoff, esrc);

    k_gemm1<<<(N_NODES + GBM - 1) / GBM, 256, 0, stream>>>(x, WbT, dis, hbuf, N_NODES);

    k_gather1<<<(N_NODES + 7) / 8, 256, 0, stream>>>(
        (const ushort4*)hbuf, rowoff, esrc, dis, b1, (ushort4*)hid);

    k_gemm2<<<(N_NODES + GBM2 - 1) / GBM2, 256, 0, stream>>>(hid, W2T, dis, h23, N_NODES);

    k_gather2<<<(N_NODES + 15) / 16, 256, 0, stream>>>(
        (const ushort4*)h23, rowoff, esrc, dis, bmu, bls, (float4*)d_out);
}

// Round 15
// 183.136 us; speedup vs baseline: 1.5412x; 1.5412x over previous
//
#include <hip/hip_runtime.h>

#define N_NODES 50000
#define NIN 512
#define NH 96
#define NL 32
#define NH2 64

#define SCAN_BLK 49
#define NB2 196          // coarse buckets of 256 nodes
#define NBLK 128         // pass-A blocks

typedef __attribute__((ext_vector_type(8))) short short8v;   // 8 bf16 (4 VGPR)
typedef __attribute__((ext_vector_type(4))) float f32x4;

__device__ __forceinline__ unsigned short f2bf(float f) {    // RNE f32->bf16
    unsigned u = __float_as_uint(f);
    u = (u + 0x7FFFu + ((u >> 16) & 1u)) >> 16;
    return (unsigned short)u;
}
__device__ __forceinline__ float bf2f(unsigned short h) {
    return __uint_as_float((unsigned)h << 16);
}

// fused: WbT = W1^T bf16; W2T = [Wmu|Wls]^T bf16; degi = 0; gcur = 0
__global__ __launch_bounds__(256) void k_prep(const float* __restrict__ W1,
                                              const float* __restrict__ Wmu,
                                              const float* __restrict__ Wls,
                                              unsigned short* __restrict__ WbT,
                                              unsigned short* __restrict__ W2T,
                                              int* __restrict__ degi,
                                              int* __restrict__ gcur) {
    int idx = blockIdx.x * 256 + threadIdx.x;
    if (idx < NH * NIN) {
        int n = idx >> 9, k = idx & 511;
        WbT[idx] = f2bf(W1[(size_t)k * NH + n]);
    } else if (idx < NH * NIN + NH2 * NH) {
        int j = idx - NH * NIN;
        int n = j / NH, k = j - n * NH;
        float v = (n < NL) ? Wmu[k * NL + n] : Wls[k * NL + (n - NL)];
        W2T[j] = f2bf(v);
    }
    if (idx < N_NODES) degi[idx] = 0;
    if (idx < NB2) gcur[idx] = 0;
}

__global__ void k_degi(const int* __restrict__ dst, int* __restrict__ degi, int E) {
    int i = blockIdx.x * blockDim.x + threadIdx.x;
    if (i < E) atomicAdd(&degi[dst[i]], 1);
}

__global__ __launch_bounds__(256) void k_scan1(const int* __restrict__ degi,
                                               int* __restrict__ bsum) {
    __shared__ int red[256];
    int t = threadIdx.x;
    int q = blockIdx.x * 256 + t;
    int s = 0;
    if (q * 4 + 3 < N_NODES) {
        int4 v = reinterpret_cast<const int4*>(degi)[q];
        s = v.x + v.y + v.z + v.w;
    } else {
        for (int j = q * 4; j < min(q * 4 + 4, N_NODES); j++) s += degi[j];
    }
    red[t] = s;
    __syncthreads();
    for (int off = 128; off > 0; off >>= 1) {
        if (t < off) red[t] += red[t + off];
        __syncthreads();
    }
    if (t == 0) bsum[blockIdx.x] = red[0];
}

__global__ __launch_bounds__(64) void k_scan2(const int* __restrict__ bsum,
                                              int* __restrict__ boff) {
    int lane = threadIdx.x;
    int v = (lane < SCAN_BLK) ? bsum[lane] : 0;
    int orig = v;
    for (int off = 1; off < 64; off <<= 1) {
        int w = __shfl_up(v, off, 64);
        if (lane >= off) v += w;
    }
    if (lane < SCAN_BLK) boff[lane] = v - orig;
}

__global__ __launch_bounds__(256) void k_scan3(const int* __restrict__ degi,
                                               const int* __restrict__ boff,
                                               int* __restrict__ rowoff,
                                               float* __restrict__ dis) {
    __shared__ int sums[256];
    int t = threadIdx.x;
    int q = blockIdx.x * 256 + t;
    int d[4] = {0, 0, 0, 0};
    if (q * 4 + 3 < N_NODES) {
        int4 v = reinterpret_cast<const int4*>(degi)[q];
        d[0] = v.x; d[1] = v.y; d[2] = v.z; d[3] = v.w;
    } else {
        for (int j = 0; j < 4; j++)
            if (q * 4 + j < N_NODES) d[j] = degi[q * 4 + j];
    }
    int tsum = d[0] + d[1] + d[2] + d[3];
    sums[t] = tsum;
    __syncthreads();
    for (int off = 1; off < 256; off <<= 1) {
        int v = (t >= off) ? sums[t - off] : 0;
        __syncthreads();
        sums[t] += v;
        __syncthreads();
    }
    int run = boff[blockIdx.x] + sums[t] - tsum;
#pragma unroll
    for (int j = 0; j < 4; j++) {
        int i = q * 4 + j;
        if (i < N_NODES) {
            rowoff[i] = run;
            dis[i] = rsqrtf((float)d[j] + 1.0f);
            run += d[j];
            if (i == N_NODES - 1) rowoff[N_NODES] = run;
        }
    }
}

// pass A: privatized block-run binning into 256-node coarse regions.
// Each block histograms its chunk (LDS), reserves one run per bucket with a
// single global atomic, then writes its runs CONTIGUOUSLY -> each cache line
// owned by one block/XCD (r14's interleaved appends caused 7x writeback
// amplification across non-coherent XCD L2s).
__global__ __launch_bounds__(256) void k_coarse(const int* __restrict__ src,
                                                const int* __restrict__ dst,
                                                const int* __restrict__ rowoff,
                                                int* __restrict__ gcur,
                                                uint2* __restrict__ cpair, int E) {
    __shared__ int hist[NB2];
    __shared__ int lpos[NB2];
    int t = threadIdx.x;
    int ch = (E + NBLK - 1) / NBLK;
    int e0 = blockIdx.x * ch, e1 = min(e0 + ch, E);
    for (int b = t; b < NB2; b += 256) hist[b] = 0;
    __syncthreads();
    for (int e = e0 + t; e < e1; e += 256)
        atomicAdd(&hist[dst[e] >> 8], 1);
    __syncthreads();
    for (int b = t; b < NB2; b += 256) {
        int cnt = hist[b];
        int base = (cnt > 0) ? atomicAdd(&gcur[b], cnt) : 0;
        lpos[b] = rowoff[b << 8] + base;     // absolute cpair index for this run
    }
    __syncthreads();
    for (int e = e0 + t; e < e1; e += 256) {
        int s = src[e], d = dst[e];
        int pos = atomicAdd(&lpos[d >> 8], 1);
        cpair[pos] = make_uint2((unsigned)s, (unsigned)d);
    }
}

// pass B: one block per coarse bucket; LDS per-node counters; esrc writes land
// in the bucket's private ~16KB window (single-XCD-owned lines).
__global__ __launch_bounds__(256) void k_fine(const uint2* __restrict__ cpair,
                                              const int* __restrict__ rowoff,
                                              int* __restrict__ esrc) {
    __shared__ int lcur[256];
    int bb = blockIdx.x;
    int n0 = bb << 8;
    int t = threadIdx.x;
    lcur[t] = 0;
    __syncthreads();
    int p0 = rowoff[n0];
    int p1 = rowoff[min(n0 + 256, N_NODES)];
    for (int p = p0 + t; p < p1; p += 256) {
        uint2 ed = cpair[p];
        int d = (int)ed.y;
        int pos = rowoff[d] + atomicAdd(&lcur[d - n0], 1);
        esrc[pos] = (int)ed.x;
    }
}

// h' = (x @ W1) * dis[row], bf16 MFMA 16x16x32 (r12 measured-best config).
// BM=128 (4 waves x 32 rows), BK=64, 8 K-tiles; LDS rows 128B, slot ^= (row&7).
#define GBM 128
__global__ __launch_bounds__(256, 2) void k_gemm1(const float* __restrict__ x,
                                                  const unsigned short* __restrict__ WbT,
                                                  const float* __restrict__ dis,
                                                  unsigned short* __restrict__ hb, int M) {
    __shared__ __align__(16) char lA[128 * 128];   // 16 KB
    __shared__ __align__(16) char lB[96 * 128];    // 12 KB
    int tid = threadIdx.x;
    int lane = tid & 63, w = tid >> 6;
    int l15 = lane & 15, hi = lane >> 4;
    int m0 = blockIdx.x * GBM;

    f32x4 acc[2][6];
#pragma unroll
    for (int rt = 0; rt < 2; ++rt)
#pragma unroll
        for (int nt = 0; nt < 6; ++nt)
#pragma unroll
            for (int i = 0; i < 4; ++i) acc[rt][nt][i] = 0.f;

    int key = l15 & 7;
    int arow0 = (w * 32 + l15) * 128;
    int arow1 = (w * 32 + 16 + l15) * 128;

    for (int kt = 0; kt < 8; ++kt) {
        __syncthreads();
#pragma unroll
        for (int i = 0; i < 4; ++i) {
            int s = i * 256 + tid;
            int r = s >> 3, sl = s & 7;
            const float* p = x + (size_t)min(m0 + r, M - 1) * NIN + kt * 64 + sl * 8;
            float4 a0 = *reinterpret_cast<const float4*>(p);
            float4 a1 = *reinterpret_cast<const float4*>(p + 4);
            uint4 pk;
            pk.x = (unsigned)f2bf(a0.x) | ((unsigned)f2bf(a0.y) << 16);
            pk.y = (unsigned)f2bf(a0.z) | ((unsigned)f2bf(a0.w) << 16);
            pk.z = (unsigned)f2bf(a1.x) | ((unsigned)f2bf(a1.y) << 16);
            pk.w = (unsigned)f2bf(a1.z) | ((unsigned)f2bf(a1.w) << 16);
            *reinterpret_cast<uint4*>(lA + r * 128 + ((sl ^ (r & 7)) << 4)) = pk;
        }
#pragma unroll
        for (int i = 0; i < 3; ++i) {
            int s = i * 256 + tid;
            int n = s >> 3, sl = s & 7;
            uint4 bv = *reinterpret_cast<const uint4*>(WbT + (size_t)n * NIN + kt * 64 + sl * 8);
            *reinterpret_cast<uint4*>(lB + n * 128 + ((sl ^ (n & 7)) << 4)) = bv;
        }
        __syncthreads();

#pragma unroll
        for (int kc = 0; kc < 2; ++kc) {
            int off = (((kc * 4 + hi) ^ key) << 4);
            short8v a0 = *reinterpret_cast<const short8v*>(lA + arow0 + off);
            short8v a1 = *reinterpret_cast<const short8v*>(lA + arow1 + off);
#pragma unroll
            for (int nt = 0; nt < 6; ++nt) {
                short8v bv = *reinterpret_cast<const short8v*>(lB + (nt * 16 + l15) * 128 + off);
                acc[0][nt] = __builtin_amdgcn_mfma_f32_16x16x32_bf16(a0, bv, acc[0][nt], 0, 0, 0);
                acc[1][nt] = __builtin_amdgcn_mfma_f32_16x16x32_bf16(a1, bv, acc[1][nt], 0, 0, 0);
            }
        }
    }

#pragma unroll
    for (int rt = 0; rt < 2; ++rt) {
        int rbase = m0 + w * 32 + rt * 16 + hi * 4;
#pragma unroll
        for (int r = 0; r < 4; ++r) {
            int orow = rbase + r;
            if (orow < M) {
                float dv = dis[orow];
                unsigned short* op = hb + (size_t)orow * NH + l15;
#pragma unroll
                for (int nt = 0; nt < 6; ++nt) op[nt * 16] = f2bf(acc[rt][nt][r] * dv);
            }
        }
    }
}

// gather layer 1 (bf16 rows, 192B): hid = relu((sum h'[s] + h'[i]) * dis + b1)
__global__ __launch_bounds__(256) void k_gather1(const ushort4* __restrict__ hb4,
                                                 const int* __restrict__ rowoff,
                                                 const int* __restrict__ esrc,
                                                 const float* __restrict__ dis,
                                                 const float* __restrict__ b1,
                                                 ushort4* __restrict__ hid4) {
    int tid = threadIdx.x;
    int node = blockIdx.x * 8 + (tid >> 5);
    int c = tid & 31;
    if (node >= N_NODES) return;
    int p0 = rowoff[node], p1 = rowoff[node + 1];
    bool act = (c < 24);
    float ax = 0.f, ay = 0.f, az = 0.f, aw = 0.f;
    for (int pb = p0; pb < p1; pb += 32) {
        int nb = min(32, p1 - pb);
        int sv = (c < nb) ? esrc[pb + c] : 0;
#pragma unroll 4
        for (int j = 0; j < nb; j++) {
            int s = __shfl(sv, j, 32);
            if (act) {
                ushort4 v = hb4[(size_t)s * 24 + c];
                ax += bf2f(v.x); ay += bf2f(v.y); az += bf2f(v.z); aw += bf2f(v.w);
            }
        }
    }
    if (act) {
        float dv = dis[node];
        ushort4 hv = hb4[(size_t)node * 24 + c];
        float4 bv = reinterpret_cast<const float4*>(b1)[c];
        ushort4 o;
        o.x = f2bf(fmaxf((ax + bf2f(hv.x)) * dv + bv.x, 0.f));
        o.y = f2bf(fmaxf((ay + bf2f(hv.y)) * dv + bv.y, 0.f));
        o.z = f2bf(fmaxf((az + bf2f(hv.z)) * dv + bv.z, 0.f));
        o.w = f2bf(fmaxf((aw + bf2f(hv.w)) * dv + bv.w, 0.f));
        hid4[(size_t)node * 24 + c] = o;
    }
}

// h23' = (hid @ W2) * dis[row], bf16 MFMA, LDS-free (W2T 12KB L1-hot)
#define GBM2 64
__global__ __launch_bounds__(256) void k_gemm2(const unsigned short* __restrict__ hid,
                                               const unsigned short* __restrict__ W2T,
                                               const float* __restrict__ dis,
                                               unsigned short* __restrict__ h23, int M) {
    int tid = threadIdx.x;
    int lane = tid & 63, w = tid >> 6;
    int l15 = lane & 15, hi = lane >> 4;
    int m0 = blockIdx.x * GBM2;
    int row = m0 + w * 16 + l15;
    const unsigned short* ap = hid + (size_t)min(row, M - 1) * NH + hi * 8;
    const unsigned short* bp = W2T + (size_t)l15 * NH + hi * 8;

    f32x4 acc[4];
#pragma unroll
    for (int nt = 0; nt < 4; ++nt)
#pragma unroll
        for (int i = 0; i < 4; ++i) acc[nt][i] = 0.f;

#pragma unroll
    for (int kc = 0; kc < 3; ++kc) {
        short8v av = *reinterpret_cast<const short8v*>(ap + kc * 32);
#pragma unroll
        for (int nt = 0; nt < 4; ++nt) {
            short8v bv = *reinterpret_cast<const short8v*>(bp + nt * 16 * NH + kc * 32);
            acc[nt] = __builtin_amdgcn_mfma_f32_16x16x32_bf16(av, bv, acc[nt], 0, 0, 0);
        }
    }

    int rbase = m0 + w * 16 + hi * 4;
#pragma unroll
    for (int r = 0; r < 4; ++r) {
        int orow = rbase + r;
        if (orow < M) {
            float dv = dis[orow];
            unsigned short* op = h23 + (size_t)orow * NH2 + l15;
#pragma unroll
            for (int nt = 0; nt < 4; ++nt) op[nt * 16] = f2bf(acc[nt][r] * dv);
        }
    }
}

// gather layer 2 (bf16 rows, 128B): out = (sum h23'[s] + h23'[i]) * dis + bias
__global__ __launch_bounds__(256) void k_gather2(const ushort4* __restrict__ hb4,
                                                 const int* __restrict__ rowoff,
                                                 const int* __restrict__ esrc,
                                                 const float* __restrict__ dis,
                                                 const float* __restrict__ bmu,
                                                 const float* __restrict__ bls,
                                                 float4* __restrict__ out4) {
    int tid = threadIdx.x;
    int node = blockIdx.x * 16 + (tid >> 4);
    int c = tid & 15;
    if (node >= N_NODES) return;
    int p0 = rowoff[node], p1 = rowoff[node + 1];
    float ax = 0.f, ay = 0.f, az = 0.f, aw = 0.f;
    for (int pb = p0; pb < p1; pb += 16) {
        int nb = min(16, p1 - pb);
        int sv = (c < nb) ? esrc[pb + c] : 0;
#pragma unroll 4
        for (int j = 0; j < nb; j++) {
            int s = __shfl(sv, j, 16);
            ushort4 v = hb4[(size_t)s * 16 + c];
            ax += bf2f(v.x); ay += bf2f(v.y); az += bf2f(v.z); aw += bf2f(v.w);
        }
    }
    float dv = dis[node];
    ushort4 hv = hb4[(size_t)node * 16 + c];
    float4 bv = (c < 8) ? reinterpret_cast<const float4*>(bmu)[c]
                        : reinterpret_cast<const float4*>(bls)[c - 8];
    float4 o;
    o.x = (ax + bf2f(hv.x)) * dv + bv.x;
    o.y = (ay + bf2f(hv.y)) * dv + bv.y;
    o.z = (az + bf2f(hv.z)) * dv + bv.z;
    o.w = (aw + bf2f(hv.w)) * dv + bv.w;
    if (c < 8) out4[(size_t)node * 8 + c] = o;
    else       out4[(size_t)N_NODES * 8 + (size_t)node * 8 + (c - 8)] = o;
}

extern "C" void kernel_launch(void* const* d_in, const int* in_sizes, int n_in,
                              void* d_out, int out_size, void* d_ws, size_t ws_size,
                              hipStream_t stream) {
    const float* x   = (const float*)d_in[0];
    const float* W1  = (const float*)d_in[1];
    const float* b1  = (const float*)d_in[2];
    const float* Wmu = (const float*)d_in[3];
    const float* bmu = (const float*)d_in[4];
    const float* Wls = (const float*)d_in[5];
    const float* bls = (const float*)d_in[6];
    const int*   ei  = (const int*)d_in[7];
    int E = in_sizes[7] / 2;
    const int* src  = ei;
    const int* dstp = ei + E;

    char* w = (char*)d_ws;
    int* degi    = (int*)w;            w += (size_t)N_NODES * 4;
    int* rowoff  = (int*)w;            w += ((size_t)N_NODES + 4) * 4;
    float* dis   = (float*)w;          w += (size_t)N_NODES * 4;
    int* bsum    = (int*)w;            w += 64 * 4;
    int* boff    = (int*)w;            w += 64 * 4;
    int* gcur    = (int*)w;            w += ((size_t)NB2 + 4) * 4;
    int* esrc    = (int*)w;            w += (size_t)E * 4;
    uint2* cpair = (uint2*)w;          w += (size_t)E * 8;
    unsigned short* WbT  = (unsigned short*)w;  w += (size_t)NH * NIN * 2;
    unsigned short* W2T  = (unsigned short*)w;  w += (size_t)NH2 * NH * 2;
    unsigned short* hbuf = (unsigned short*)w;  w += (size_t)N_NODES * NH * 2;
    unsigned short* hid  = (unsigned short*)w;  w += (size_t)N_NODES * NH * 2;
    unsigned short* h23  = (unsigned short*)w;  w += (size_t)N_NODES * NH2 * 2;

    int prep_n = NH * NIN + NH2 * NH;
    k_prep<<<(prep_n + 255) / 256, 256, 0, stream>>>(W1, Wmu, Wls, WbT, W2T, degi, gcur);

    k_degi<<<(E + 255) / 256, 256, 0, stream>>>(dstp, degi, E);
    k_scan1<<<SCAN_BLK, 256, 0, stream>>>(degi, bsum);
    k_scan2<<<1, 64, 0, stream>>>(bsum, boff);
    k_scan3<<<SCAN_BLK, 256, 0, stream>>>(degi, boff, rowoff, dis);

    k_coarse<<<NBLK, 256, 0, stream>>>(src, dstp, rowoff, gcur, cpair, E);
    k_fine<<<NB2, 256, 0, stream>>>(cpair, rowoff, esrc);

    k_gemm1<<<(N_NODES + GBM - 1) / GBM, 256, 0, stream>>>(x, WbT, dis, hbuf, N_NODES);

    k_gather1<<<(N_NODES + 7) / 8, 256, 0, stream>>>(
        (const ushort4*)hbuf, rowoff, esrc, dis, b1, (ushort4*)hid);

    k_gemm2<<<(N_NODES + GBM2 - 1) / GBM2, 256, 0, stream>>>(hid, W2T, dis, h23, N_NODES);

    k_gather2<<<(N_NODES + 15) / 16, 256, 0, stream>>>(
        (const ushort4*)h23, rowoff, esrc, dis, bmu, bls, (float4*)d_out);
}

// Round 16
// 152.276 us; speedup vs baseline: 1.8535x; 1.2027x over previous
//
#include <hip/hip_runtime.h>

#define N_NODES 50000
#define NIN 512
#define NH 96
#define NL 32
#define NH2 64

#define NB2 196          // coarse buckets of 256 nodes
#define NBLK 128         // histogram / binning blocks

typedef __attribute__((ext_vector_type(8))) short short8v;   // 8 bf16 (4 VGPR)
typedef __attribute__((ext_vector_type(4))) float f32x4;

__device__ __forceinline__ unsigned short f2bf(float f) {    // RNE f32->bf16
    unsigned u = __float_as_uint(f);
    u = (u + 0x7FFFu + ((u >> 16) & 1u)) >> 16;
    return (unsigned short)u;
}
__device__ __forceinline__ float bf2f(unsigned short h) {
    return __uint_as_float((unsigned)h << 16);
}

// fused: WbT = W1^T bf16; W2T = [Wmu|Wls]^T bf16; bcnt = gcur = 0
__global__ __launch_bounds__(256) void k_prep(const float* __restrict__ W1,
                                              const float* __restrict__ Wmu,
                                              const float* __restrict__ Wls,
                                              unsigned short* __restrict__ WbT,
                                              unsigned short* __restrict__ W2T,
                                              int* __restrict__ bcnt,
                                              int* __restrict__ gcur) {
    int idx = blockIdx.x * 256 + threadIdx.x;
    if (idx < NH * NIN) {
        int n = idx >> 9, k = idx & 511;
        WbT[idx] = f2bf(W1[(size_t)k * NH + n]);
    } else if (idx < NH * NIN + NH2 * NH) {
        int j = idx - NH * NIN;
        int n = j / NH, k = j - n * NH;
        float v = (n < NL) ? Wmu[k * NL + n] : Wls[k * NL + (n - NL)];
        W2T[j] = f2bf(v);
    }
    if (idx < NB2) { bcnt[idx] = 0; gcur[idx] = 0; }
}

// per-bucket histogram of dst (LDS-privatized; 196x128 global atomics total)
__global__ __launch_bounds__(256) void k_bhist(const int* __restrict__ dst,
                                               int* __restrict__ bcnt, int E) {
    __shared__ int hist[NB2];
    int t = threadIdx.x;
    for (int b = t; b < NB2; b += 256) hist[b] = 0;
    __syncthreads();
    int ch = (E + NBLK - 1) / NBLK;
    int e0 = blockIdx.x * ch, e1 = min(e0 + ch, E);
    for (int e = e0 + t; e < e1; e += 256)
        atomicAdd(&hist[dst[e] >> 8], 1);
    __syncthreads();
    for (int b = t; b < NB2; b += 256)
        if (hist[b]) atomicAdd(&bcnt[b], hist[b]);
}

// one block: exclusive scan of 196 bucket counts -> bbase[197]; rowoff[N] = E
__global__ __launch_bounds__(256) void k_bscan(const int* __restrict__ bcnt,
                                               int* __restrict__ bbase,
                                               int* __restrict__ rowoff) {
    __shared__ int s[256];
    int t = threadIdx.x;
    int v = (t < NB2) ? bcnt[t] : 0;
    s[t] = v;
    __syncthreads();
    for (int off = 1; off < 256; off <<= 1) {
        int u = (t >= off) ? s[t - off] : 0;
        __syncthreads();
        s[t] += u;
        __syncthreads();
    }
    if (t < NB2) bbase[t] = s[t] - v;
    if (t == NB2 - 1) { bbase[NB2] = s[t]; rowoff[N_NODES] = s[t]; }
}

// pass A: privatized block-run binning into 256-node coarse regions; packed
// (s | d<<16) single-uint payload (node ids < 65536). Runs are contiguous ->
// each cache line owned by one block/XCD (r14 lesson).
__global__ __launch_bounds__(256) void k_coarse(const int* __restrict__ src,
                                                const int* __restrict__ dst,
                                                const int* __restrict__ bbase,
                                                int* __restrict__ gcur,
                                                unsigned* __restrict__ cpair, int E) {
    __shared__ int hist[NB2];
    __shared__ int lpos[NB2];
    int t = threadIdx.x;
    int ch = (E + NBLK - 1) / NBLK;
    int e0 = blockIdx.x * ch, e1 = min(e0 + ch, E);
    for (int b = t; b < NB2; b += 256) hist[b] = 0;
    __syncthreads();
    for (int e = e0 + t; e < e1; e += 256)
        atomicAdd(&hist[dst[e] >> 8], 1);
    __syncthreads();
    for (int b = t; b < NB2; b += 256) {
        int cnt = hist[b];
        int base = (cnt > 0) ? atomicAdd(&gcur[b], cnt) : 0;
        lpos[b] = bbase[b] + base;
    }
    __syncthreads();
    for (int e = e0 + t; e < e1; e += 256) {
        int s = src[e], d = dst[e];
        int pos = atomicAdd(&lpos[d >> 8], 1);
        cpair[pos] = (unsigned)s | ((unsigned)d << 16);
    }
}

// pass B: one block per bucket. Derives per-node counts (LDS), scans them to
// produce rowoff+dis (k_degi and the global scans are deleted), then places
// edges into the bucket's private esrc window.
__global__ __launch_bounds__(256) void k_fine(const unsigned* __restrict__ cpair,
                                              const int* __restrict__ bbase,
                                              int* __restrict__ rowoff,
                                              float* __restrict__ dis,
                                              int* __restrict__ esrc) {
    __shared__ int lcnt[256];
    __shared__ int lscan[256];
    int bb = blockIdx.x;
    int n0 = bb << 8;
    int t = threadIdx.x;
    lcnt[t] = 0;
    __syncthreads();
    int p0 = bbase[bb], p1 = bbase[bb + 1];
    for (int p = p0 + t; p < p1; p += 256)
        atomicAdd(&lcnt[(cpair[p] >> 16) - n0], 1);
    __syncthreads();
    int cnt = lcnt[t];
    lscan[t] = cnt;
    __syncthreads();
    for (int off = 1; off < 256; off <<= 1) {
        int u = (t >= off) ? lscan[t - off] : 0;
        __syncthreads();
        lscan[t] += u;
        __syncthreads();
    }
    int excl = lscan[t] - cnt;
    int node = n0 + t;
    if (node < N_NODES) {
        rowoff[node] = p0 + excl;
        dis[node] = rsqrtf((float)cnt + 1.0f);
    }
    lcnt[t] = p0 + excl;                 // running absolute position
    __syncthreads();
    for (int p = p0 + t; p < p1; p += 256) {
        unsigned u = cpair[p];
        int d = (int)(u >> 16);
        int pos = atomicAdd(&lcnt[d - n0], 1);
        esrc[pos] = (int)(u & 0xFFFFu);
    }
}

// h' = (x @ W1) * dis[row], bf16 MFMA 16x16x32.
// BM=64 (4 waves x 16 rows), BK=64, 8 K-tiles -> 782 blocks = 3 blocks/CU
// (r12's BM=128 had 391 blocks = 1.5/CU: latency exposed, r13 prefetch null).
// LDS rows 128B, slot ^= (row&7): conflict-free frag reads, coalesced staging.
#define GBM 64
__global__ __launch_bounds__(256, 3) void k_gemm1(const float* __restrict__ x,
                                                  const unsigned short* __restrict__ WbT,
                                                  const float* __restrict__ dis,
                                                  unsigned short* __restrict__ hb, int M) {
    __shared__ __align__(16) char lA[64 * 128];    // 8 KB
    __shared__ __align__(16) char lB[96 * 128];    // 12 KB
    int tid = threadIdx.x;
    int lane = tid & 63, w = tid >> 6;
    int l15 = lane & 15, hi = lane >> 4;
    int m0 = blockIdx.x * GBM;

    f32x4 acc[6];
#pragma unroll
    for (int nt = 0; nt < 6; ++nt)
#pragma unroll
        for (int i = 0; i < 4; ++i) acc[nt][i] = 0.f;

    int key = l15 & 7;
    int arow = (w * 16 + l15) * 128;

    for (int kt = 0; kt < 8; ++kt) {
        __syncthreads();
#pragma unroll
        for (int i = 0; i < 2; ++i) {      // A: 512 slots (64 rows x 8), 2/thread
            int s = i * 256 + tid;
            int r = s >> 3, sl = s & 7;
            const float* p = x + (size_t)min(m0 + r, M - 1) * NIN + kt * 64 + sl * 8;
            float4 a0 = *reinterpret_cast<const float4*>(p);
            float4 a1 = *reinterpret_cast<const float4*>(p + 4);
            uint4 pk;
            pk.x = (unsigned)f2bf(a0.x) | ((unsigned)f2bf(a0.y) << 16);
            pk.y = (unsigned)f2bf(a0.z) | ((unsigned)f2bf(a0.w) << 16);
            pk.z = (unsigned)f2bf(a1.x) | ((unsigned)f2bf(a1.y) << 16);
            pk.w = (unsigned)f2bf(a1.z) | ((unsigned)f2bf(a1.w) << 16);
            *reinterpret_cast<uint4*>(lA + r * 128 + ((sl ^ (r & 7)) << 4)) = pk;
        }
#pragma unroll
        for (int i = 0; i < 3; ++i) {      // B: 768 slots (96 rows x 8), 3/thread
            int s = i * 256 + tid;
            int n = s >> 3, sl = s & 7;
            uint4 bv = *reinterpret_cast<const uint4*>(WbT + (size_t)n * NIN + kt * 64 + sl * 8);
            *reinterpret_cast<uint4*>(lB + n * 128 + ((sl ^ (n & 7)) << 4)) = bv;
        }
        __syncthreads();

#pragma unroll
        for (int kc = 0; kc < 2; ++kc) {
            int off = (((kc * 4 + hi) ^ key) << 4);
            short8v a = *reinterpret_cast<const short8v*>(lA + arow + off);
#pragma unroll
            for (int nt = 0; nt < 6; ++nt) {
                short8v bv = *reinterpret_cast<const short8v*>(lB + (nt * 16 + l15) * 128 + off);
                acc[nt] = __builtin_amdgcn_mfma_f32_16x16x32_bf16(a, bv, acc[nt], 0, 0, 0);
            }
        }
    }

    // C: row=(lane>>4)*4+reg, col=lane&15 (m89-verified); fuse dis scale, bf16 out
    int rbase = m0 + w * 16 + hi * 4;
#pragma unroll
    for (int r = 0; r < 4; ++r) {
        int orow = rbase + r;
        if (orow < M) {
            float dv = dis[orow];
            unsigned short* op = hb + (size_t)orow * NH + l15;
#pragma unroll
            for (int nt = 0; nt < 6; ++nt) op[nt * 16] = f2bf(acc[nt][r] * dv);
        }
    }
}

// gather layer 1 (bf16 rows, 192B): hid = relu((sum h'[s] + h'[i]) * dis + b1)
__global__ __launch_bounds__(256) void k_gather1(const ushort4* __restrict__ hb4,
                                                 const int* __restrict__ rowoff,
                                                 const int* __restrict__ esrc,
                                                 const float* __restrict__ dis,
                                                 const float* __restrict__ b1,
                                                 ushort4* __restrict__ hid4) {
    int tid = threadIdx.x;
    int node = blockIdx.x * 8 + (tid >> 5);
    int c = tid & 31;
    if (node >= N_NODES) return;
    int p0 = rowoff[node], p1 = rowoff[node + 1];
    bool act = (c < 24);
    float ax = 0.f, ay = 0.f, az = 0.f, aw = 0.f;
    for (int pb = p0; pb < p1; pb += 32) {
        int nb = min(32, p1 - pb);
        int sv = (c < nb) ? esrc[pb + c] : 0;
#pragma unroll 4
        for (int j = 0; j < nb; j++) {
            int s = __shfl(sv, j, 32);
            if (act) {
                ushort4 v = hb4[(size_t)s * 24 + c];
                ax += bf2f(v.x); ay += bf2f(v.y); az += bf2f(v.z); aw += bf2f(v.w);
            }
        }
    }
    if (act) {
        float dv = dis[node];
        ushort4 hv = hb4[(size_t)node * 24 + c];
        float4 bv = reinterpret_cast<const float4*>(b1)[c];
        ushort4 o;
        o.x = f2bf(fmaxf((ax + bf2f(hv.x)) * dv + bv.x, 0.f));
        o.y = f2bf(fmaxf((ay + bf2f(hv.y)) * dv + bv.y, 0.f));
        o.z = f2bf(fmaxf((az + bf2f(hv.z)) * dv + bv.z, 0.f));
        o.w = f2bf(fmaxf((aw + bf2f(hv.w)) * dv + bv.w, 0.f));
        hid4[(size_t)node * 24 + c] = o;
    }
}

// h23' = (hid @ W2) * dis[row], bf16 MFMA, LDS-free (W2T 12KB L1-hot)
#define GBM2 64
__global__ __launch_bounds__(256) void k_gemm2(const unsigned short* __restrict__ hid,
                                               const unsigned short* __restrict__ W2T,
                                               const float* __restrict__ dis,
                                               unsigned short* __restrict__ h23, int M) {
    int tid = threadIdx.x;
    int lane = tid & 63, w = tid >> 6;
    int l15 = lane & 15, hi = lane >> 4;
    int m0 = blockIdx.x * GBM2;
    int row = m0 + w * 16 + l15;
    const unsigned short* ap = hid + (size_t)min(row, M - 1) * NH + hi * 8;
    const unsigned short* bp = W2T + (size_t)l15 * NH + hi * 8;

    f32x4 acc[4];
#pragma unroll
    for (int nt = 0; nt < 4; ++nt)
#pragma unroll
        for (int i = 0; i < 4; ++i) acc[nt][i] = 0.f;

#pragma unroll
    for (int kc = 0; kc < 3; ++kc) {
        short8v av = *reinterpret_cast<const short8v*>(ap + kc * 32);
#pragma unroll
        for (int nt = 0; nt < 4; ++nt) {
            short8v bv = *reinterpret_cast<const short8v*>(bp + nt * 16 * NH + kc * 32);
            acc[nt] = __builtin_amdgcn_mfma_f32_16x16x32_bf16(av, bv, acc[nt], 0, 0, 0);
        }
    }

    int rbase = m0 + w * 16 + hi * 4;
#pragma unroll
    for (int r = 0; r < 4; ++r) {
        int orow = rbase + r;
        if (orow < M) {
            float dv = dis[orow];
            unsigned short* op = h23 + (size_t)orow * NH2 + l15;
#pragma unroll
            for (int nt = 0; nt < 4; ++nt) op[nt * 16] = f2bf(acc[nt][r] * dv);
        }
    }
}

// gather layer 2 (bf16 rows, 128B): out = (sum h23'[s] + h23'[i]) * dis + bias
__global__ __launch_bounds__(256) void k_gather2(const ushort4* __restrict__ hb4,
                                                 const int* __restrict__ rowoff,
                                                 const int* __restrict__ esrc,
                                                 const float* __restrict__ dis,
                                                 const float* __restrict__ bmu,
                                                 const float* __restrict__ bls,
                                                 float4* __restrict__ out4) {
    int tid = threadIdx.x;
    int node = blockIdx.x * 16 + (tid >> 4);
    int c = tid & 15;
    if (node >= N_NODES) return;
    int p0 = rowoff[node], p1 = rowoff[node + 1];
    float ax = 0.f, ay = 0.f, az = 0.f, aw = 0.f;
    for (int pb = p0; pb < p1; pb += 16) {
        int nb = min(16, p1 - pb);
        int sv = (c < nb) ? esrc[pb + c] : 0;
#pragma unroll 4
        for (int j = 0; j < nb; j++) {
            int s = __shfl(sv, j, 16);
            ushort4 v = hb4[(size_t)s * 16 + c];
            ax += bf2f(v.x); ay += bf2f(v.y); az += bf2f(v.z); aw += bf2f(v.w);
        }
    }
    float dv = dis[node];
    ushort4 hv = hb4[(size_t)node * 16 + c];
    float4 bv = (c < 8) ? reinterpret_cast<const float4*>(bmu)[c]
                        : reinterpret_cast<const float4*>(bls)[c - 8];
    float4 o;
    o.x = (ax + bf2f(hv.x)) * dv + bv.x;
    o.y = (ay + bf2f(hv.y)) * dv + bv.y;
    o.z = (az + bf2f(hv.z)) * dv + bv.z;
    o.w = (aw + bf2f(hv.w)) * dv + bv.w;
    if (c < 8) out4[(size_t)node * 8 + c] = o;
    else       out4[(size_t)N_NODES * 8 + (size_t)node * 8 + (c - 8)] = o;
}

extern "C" void kernel_launch(void* const* d_in, const int* in_sizes, int n_in,
                              void* d_out, int out_size, void* d_ws, size_t ws_size,
                              hipStream_t stream) {
    const float* x   = (const float*)d_in[0];
    const float* W1  = (const float*)d_in[1];
    const float* b1  = (const float*)d_in[2];
    const float* Wmu = (const float*)d_in[3];
    const float* bmu = (const float*)d_in[4];
    const float* Wls = (const float*)d_in[5];
    const float* bls = (const float*)d_in[6];
    const int*   ei  = (const int*)d_in[7];
    int E = in_sizes[7] / 2;
    const int* src  = ei;
    const int* dstp = ei + E;

    char* w = (char*)d_ws;
    int* rowoff  = (int*)w;            w += ((size_t)N_NODES + 4) * 4;
    float* dis   = (float*)w;          w += (size_t)N_NODES * 4;
    int* bcnt    = (int*)w;            w += ((size_t)NB2 + 4) * 4;
    int* bbase   = (int*)w;            w += ((size_t)NB2 + 4) * 4;
    int* gcur    = (int*)w;            w += ((size_t)NB2 + 4) * 4;
    int* esrc    = (int*)w;            w += (size_t)E * 4;
    unsigned* cpair = (unsigned*)w;    w += (size_t)E * 4;
    unsigned short* WbT  = (unsigned short*)w;  w += (size_t)NH * NIN * 2;
    unsigned short* W2T  = (unsigned short*)w;  w += (size_t)NH2 * NH * 2;
    unsigned short* hbuf = (unsigned short*)w;  w += (size_t)N_NODES * NH * 2;
    unsigned short* hid  = (unsigned short*)w;  w += (size_t)N_NODES * NH * 2;
    unsigned short* h23  = (unsigned short*)w;  w += (size_t)N_NODES * NH2 * 2;

    int prep_n = NH * NIN + NH2 * NH;
    k_prep<<<(prep_n + 255) / 256, 256, 0, stream>>>(W1, Wmu, Wls, WbT, W2T, bcnt, gcur);

    k_bhist<<<NBLK, 256, 0, stream>>>(dstp, bcnt, E);
    k_bscan<<<1, 256, 0, stream>>>(bcnt, bbase, rowoff);
    k_coarse<<<NBLK, 256, 0, stream>>>(src, dstp, bbase, gcur, cpair, E);
    k_fine<<<NB2, 256, 0, stream>>>(cpair, bbase, rowoff, dis, esrc);

    k_gemm1<<<(N_NODES + GBM - 1) / GBM, 256, 0, stream>>>(x, WbT, dis, hbuf, N_NODES);

    k_gather1<<<(N_NODES + 7) / 8, 256, 0, stream>>>(
        (const ushort4*)hbuf, rowoff, esrc, dis, b1, (ushort4*)hid);

    k_gemm2<<<(N_NODES + GBM2 - 1) / GBM2, 256, 0, stream>>>(hid, W2T, dis, h23, N_NODES);

    k_gather2<<<(N_NODES + 15) / 16, 256, 0, stream>>>(
        (const ushort4*)h23, rowoff, esrc, dis, bmu, bls, (float4*)d_out);
}

// Round 17
// 142.267 us; speedup vs baseline: 1.9839x; 1.0704x over previous
//
#include <hip/hip_runtime.h>

#define N_NODES 50000
#define NIN 512
#define NH 96
#define NL 32
#define NH2 64

#define NB2 196          // coarse buckets of 256 nodes
#define NBLK 128         // binning blocks
#define BCAP 5120        // fixed region capacity per bucket (E[cnt]=4096, +16 sigma)

typedef __attribute__((ext_vector_type(8))) short short8v;   // 8 bf16 (4 VGPR)
typedef __attribute__((ext_vector_type(4))) float f32x4;

__device__ __forceinline__ unsigned short f2bf(float f) {    // RNE f32->bf16
    unsigned u = __float_as_uint(f);
    u = (u + 0x7FFFu + ((u >> 16) & 1u)) >> 16;
    return (unsigned short)u;
}
__device__ __forceinline__ float bf2f(unsigned short h) {
    return __uint_as_float((unsigned)h << 16);
}

// fused: WbT = W1^T bf16; W2T = [Wmu|Wls]^T bf16; gcur = 0
__global__ __launch_bounds__(256) void k_prep(const float* __restrict__ W1,
                                              const float* __restrict__ Wmu,
                                              const float* __restrict__ Wls,
                                              unsigned short* __restrict__ WbT,
                                              unsigned short* __restrict__ W2T,
                                              int* __restrict__ gcur) {
    int idx = blockIdx.x * 256 + threadIdx.x;
    if (idx < NH * NIN) {
        int n = idx >> 9, k = idx & 511;
        WbT[idx] = f2bf(W1[(size_t)k * NH + n]);
    } else if (idx < NH * NIN + NH2 * NH) {
        int j = idx - NH * NIN;
        int n = j / NH, k = j - n * NH;
        float v = (n < NL) ? Wmu[k * NL + n] : Wls[k * NL + (n - NL)];
        W2T[j] = f2bf(v);
    }
    if (idx < NB2) gcur[idx] = 0;
}

// pass A: privatized block-run binning into FIXED-CAPACITY bucket regions
// (no bbase dependency -> k_bhist deleted). Runs contiguous -> each cache
// line owned by one block/XCD (r14 lesson). Packed (s | d<<16) payload.
__global__ __launch_bounds__(256) void k_coarse(const int* __restrict__ src,
                                                const int* __restrict__ dst,
                                                int* __restrict__ gcur,
                                                unsigned* __restrict__ cpair, int E) {
    __shared__ int hist[NB2];
    __shared__ int lpos[NB2];
    int t = threadIdx.x;
    int ch = (E + NBLK - 1) / NBLK;
    int e0 = blockIdx.x * ch, e1 = min(e0 + ch, E);
    for (int b = t; b < NB2; b += 256) hist[b] = 0;
    __syncthreads();
    for (int e = e0 + t; e < e1; e += 256)
        atomicAdd(&hist[dst[e] >> 8], 1);
    __syncthreads();
    for (int b = t; b < NB2; b += 256) {
        int cnt = hist[b];
        int base = (cnt > 0) ? atomicAdd(&gcur[b], cnt) : 0;
        lpos[b] = b * BCAP + base;
    }
    __syncthreads();
    for (int e = e0 + t; e < e1; e += 256) {
        int s = src[e], d = dst[e];
        int pos = atomicAdd(&lpos[d >> 8], 1);
        cpair[pos] = (unsigned)s | ((unsigned)d << 16);
    }
}

// one block: exclusive scan of the 196 actual bucket counts -> bbase; rowoff[N]=E
__global__ __launch_bounds__(256) void k_bscan(const int* __restrict__ gcur,
                                               int* __restrict__ bbase,
                                               int* __restrict__ rowoff) {
    __shared__ int s[256];
    int t = threadIdx.x;
    int v = (t < NB2) ? gcur[t] : 0;
    s[t] = v;
    __syncthreads();
    for (int off = 1; off < 256; off <<= 1) {
        int u = (t >= off) ? s[t - off] : 0;
        __syncthreads();
        s[t] += u;
        __syncthreads();
    }
    if (t < NB2) bbase[t] = s[t] - v;
    if (t == NB2 - 1) { bbase[NB2] = s[t]; rowoff[N_NODES] = s[t]; }
}

// pass B: one block per bucket. Derives per-node counts (LDS), scans them to
// produce rowoff+dis, then places edges into the bucket's private esrc window.
__global__ __launch_bounds__(256) void k_fine(const unsigned* __restrict__ cpair,
                                              const int* __restrict__ gcur,
                                              const int* __restrict__ bbase,
                                              int* __restrict__ rowoff,
                                              float* __restrict__ dis,
                                              int* __restrict__ esrc) {
    __shared__ int lcnt[256];
    __shared__ int lscan[256];
    int bb = blockIdx.x;
    int n0 = bb << 8;
    int t = threadIdx.x;
    lcnt[t] = 0;
    __syncthreads();
    int p0 = bb * BCAP;
    int p1 = p0 + gcur[bb];
    int base = bbase[bb];
    for (int p = p0 + t; p < p1; p += 256)
        atomicAdd(&lcnt[(cpair[p] >> 16) - n0], 1);
    __syncthreads();
    int cnt = lcnt[t];
    lscan[t] = cnt;
    __syncthreads();
    for (int off = 1; off < 256; off <<= 1) {
        int u = (t >= off) ? lscan[t - off] : 0;
        __syncthreads();
        lscan[t] += u;
        __syncthreads();
    }
    int excl = lscan[t] - cnt;
    int node = n0 + t;
    if (node < N_NODES) {
        rowoff[node] = base + excl;
        dis[node] = rsqrtf((float)cnt + 1.0f);
    }
    lcnt[t] = base + excl;               // running absolute position
    __syncthreads();
    for (int p = p0 + t; p < p1; p += 256) {
        unsigned u = cpair[p];
        int d = (int)(u >> 16);
        int pos = atomicAdd(&lcnt[d - n0], 1);
        esrc[pos] = (int)(u & 0xFFFFu);
    }
}

// h' = (x @ W1) * dis[row], bf16 MFMA 16x16x32 (r16 measured-best config).
// BM=64 (4 waves x 16 rows), BK=64, 8 K-tiles -> 782 blocks = 3 blocks/CU.
// LDS rows 128B, slot ^= (row&7): conflict-free frag reads, coalesced staging.
#define GBM 64
__global__ __launch_bounds__(256, 3) void k_gemm1(const float* __restrict__ x,
                                                  const unsigned short* __restrict__ WbT,
                                                  const float* __restrict__ dis,
                                                  unsigned short* __restrict__ hb, int M) {
    __shared__ __align__(16) char lA[64 * 128];    // 8 KB
    __shared__ __align__(16) char lB[96 * 128];    // 12 KB
    int tid = threadIdx.x;
    int lane = tid & 63, w = tid >> 6;
    int l15 = lane & 15, hi = lane >> 4;
    int m0 = blockIdx.x * GBM;

    f32x4 acc[6];
#pragma unroll
    for (int nt = 0; nt < 6; ++nt)
#pragma unroll
        for (int i = 0; i < 4; ++i) acc[nt][i] = 0.f;

    int key = l15 & 7;
    int arow = (w * 16 + l15) * 128;

    for (int kt = 0; kt < 8; ++kt) {
        __syncthreads();
#pragma unroll
        for (int i = 0; i < 2; ++i) {      // A: 512 slots (64 rows x 8), 2/thread
            int s = i * 256 + tid;
            int r = s >> 3, sl = s & 7;
            const float* p = x + (size_t)min(m0 + r, M - 1) * NIN + kt * 64 + sl * 8;
            float4 a0 = *reinterpret_cast<const float4*>(p);
            float4 a1 = *reinterpret_cast<const float4*>(p + 4);
            uint4 pk;
            pk.x = (unsigned)f2bf(a0.x) | ((unsigned)f2bf(a0.y) << 16);
            pk.y = (unsigned)f2bf(a0.z) | ((unsigned)f2bf(a0.w) << 16);
            pk.z = (unsigned)f2bf(a1.x) | ((unsigned)f2bf(a1.y) << 16);
            pk.w = (unsigned)f2bf(a1.z) | ((unsigned)f2bf(a1.w) << 16);
            *reinterpret_cast<uint4*>(lA + r * 128 + ((sl ^ (r & 7)) << 4)) = pk;
        }
#pragma unroll
        for (int i = 0; i < 3; ++i) {      // B: 768 slots (96 rows x 8), 3/thread
            int s = i * 256 + tid;
            int n = s >> 3, sl = s & 7;
            uint4 bv = *reinterpret_cast<const uint4*>(WbT + (size_t)n * NIN + kt * 64 + sl * 8);
            *reinterpret_cast<uint4*>(lB + n * 128 + ((sl ^ (n & 7)) << 4)) = bv;
        }
        __syncthreads();

#pragma unroll
        for (int kc = 0; kc < 2; ++kc) {
            int off = (((kc * 4 + hi) ^ key) << 4);
            short8v a = *reinterpret_cast<const short8v*>(lA + arow + off);
#pragma unroll
            for (int nt = 0; nt < 6; ++nt) {
                short8v bv = *reinterpret_cast<const short8v*>(lB + (nt * 16 + l15) * 128 + off);
                acc[nt] = __builtin_amdgcn_mfma_f32_16x16x32_bf16(a, bv, acc[nt], 0, 0, 0);
            }
        }
    }

    // C: row=(lane>>4)*4+reg, col=lane&15 (m89-verified); fuse dis scale, bf16 out
    int rbase = m0 + w * 16 + hi * 4;
#pragma unroll
    for (int r = 0; r < 4; ++r) {
        int orow = rbase + r;
        if (orow < M) {
            float dv = dis[orow];
            unsigned short* op = hb + (size_t)orow * NH + l15;
#pragma unroll
            for (int nt = 0; nt < 6; ++nt) op[nt * 16] = f2bf(acc[nt][r] * dv);
        }
    }
}

// gather layer 1 (bf16 rows, 192B): hid = relu((sum h'[s] + h'[i]) * dis + b1)
__global__ __launch_bounds__(256) void k_gather1(const ushort4* __restrict__ hb4,
                                                 const int* __restrict__ rowoff,
                                                 const int* __restrict__ esrc,
                                                 const float* __restrict__ dis,
                                                 const float* __restrict__ b1,
                                                 ushort4* __restrict__ hid4) {
    int tid = threadIdx.x;
    int node = blockIdx.x * 8 + (tid >> 5);
    int c = tid & 31;
    if (node >= N_NODES) return;
    int p0 = rowoff[node], p1 = rowoff[node + 1];
    bool act = (c < 24);
    float ax = 0.f, ay = 0.f, az = 0.f, aw = 0.f;
    for (int pb = p0; pb < p1; pb += 32) {
        int nb = min(32, p1 - pb);
        int sv = (c < nb) ? esrc[pb + c] : 0;
#pragma unroll 4
        for (int j = 0; j < nb; j++) {
            int s = __shfl(sv, j, 32);
            if (act) {
                ushort4 v = hb4[(size_t)s * 24 + c];
                ax += bf2f(v.x); ay += bf2f(v.y); az += bf2f(v.z); aw += bf2f(v.w);
            }
        }
    }
    if (act) {
        float dv = dis[node];
        ushort4 hv = hb4[(size_t)node * 24 + c];
        float4 bv = reinterpret_cast<const float4*>(b1)[c];
        ushort4 o;
        o.x = f2bf(fmaxf((ax + bf2f(hv.x)) * dv + bv.x, 0.f));
        o.y = f2bf(fmaxf((ay + bf2f(hv.y)) * dv + bv.y, 0.f));
        o.z = f2bf(fmaxf((az + bf2f(hv.z)) * dv + bv.z, 0.f));
        o.w = f2bf(fmaxf((aw + bf2f(hv.w)) * dv + bv.w, 0.f));
        hid4[(size_t)node * 24 + c] = o;
    }
}

// h23' = (hid @ W2) * dis[row], bf16 MFMA with LDS staging (the LDS-free
// per-lane A-reads were the r11 scatter pattern). Single K-pass, rows padded
// to 256B (16 slots), in-row XOR key (row&7) -> 2-way frag reads (free).
#define GBM2 64
__global__ __launch_bounds__(256) void k_gemm2(const unsigned short* __restrict__ hid,
                                               const unsigned short* __restrict__ W2T,
                                               const float* __restrict__ dis,
                                               unsigned short* __restrict__ h23, int M) {
    __shared__ __align__(16) char lA[64 * 256];    // 16 KB (12/16 slots used)
    __shared__ __align__(16) char lB[64 * 256];    // 16 KB
    int tid = threadIdx.x;
    int lane = tid & 63, w = tid >> 6;
    int l15 = lane & 15, hi = lane >> 4;
    int m0 = blockIdx.x * GBM2;

    // stage A: 64 rows x 12 slots = 768, 3/thread, coalesced
#pragma unroll
    for (int i = 0; i < 3; ++i) {
        int s = i * 256 + tid;
        int r = s / 12, sl = s - r * 12;
        uint4 v = *reinterpret_cast<const uint4*>(
            hid + (size_t)min(m0 + r, M - 1) * NH + sl * 8);
        *reinterpret_cast<uint4*>(lA + r * 256 + ((sl ^ (r & 7)) << 4)) = v;
    }
    // stage B: 64 rows x 12 slots = 768
#pragma unroll
    for (int i = 0; i < 3; ++i) {
        int s = i * 256 + tid;
        int n = s / 12, sl = s - n * 12;
        uint4 v = *reinterpret_cast<const uint4*>(W2T + (size_t)n * NH + sl * 8);
        *reinterpret_cast<uint4*>(lB + n * 256 + ((sl ^ (n & 7)) << 4)) = v;
    }
    __syncthreads();

    f32x4 acc[4];
#pragma unroll
    for (int nt = 0; nt < 4; ++nt)
#pragma unroll
        for (int i = 0; i < 4; ++i) acc[nt][i] = 0.f;

    int key = l15 & 7;
    const char* aptr = lA + (w * 16 + l15) * 256;
#pragma unroll
    for (int kc = 0; kc < 3; ++kc) {
        int off = (((kc * 4 + hi) ^ key) << 4);
        short8v a = *reinterpret_cast<const short8v*>(aptr + off);
#pragma unroll
        for (int nt = 0; nt < 4; ++nt) {
            short8v bv = *reinterpret_cast<const short8v*>(lB + (nt * 16 + l15) * 256 + off);
            acc[nt] = __builtin_amdgcn_mfma_f32_16x16x32_bf16(a, bv, acc[nt], 0, 0, 0);
        }
    }

    int rbase = m0 + w * 16 + hi * 4;
#pragma unroll
    for (int r = 0; r < 4; ++r) {
        int orow = rbase + r;
        if (orow < M) {
            float dv = dis[orow];
            unsigned short* op = h23 + (size_t)orow * NH2 + l15;
#pragma unroll
            for (int nt = 0; nt < 4; ++nt) op[nt * 16] = f2bf(acc[nt][r] * dv);
        }
    }
}

// gather layer 2 (bf16 rows, 128B): out = (sum h23'[s] + h23'[i]) * dis + bias
__global__ __launch_bounds__(256) void k_gather2(const ushort4* __restrict__ hb4,
                                                 const int* __restrict__ rowoff,
                                                 const int* __restrict__ esrc,
                                                 const float* __restrict__ dis,
                                                 const float* __restrict__ bmu,
                                                 const float* __restrict__ bls,
                                                 float4* __restrict__ out4) {
    int tid = threadIdx.x;
    int node = blockIdx.x * 16 + (tid >> 4);
    int c = tid & 15;
    if (node >= N_NODES) return;
    int p0 = rowoff[node], p1 = rowoff[node + 1];
    float ax = 0.f, ay = 0.f, az = 0.f, aw = 0.f;
    for (int pb = p0; pb < p1; pb += 16) {
        int nb = min(16, p1 - pb);
        int sv = (c < nb) ? esrc[pb + c] : 0;
#pragma unroll 4
        for (int j = 0; j < nb; j++) {
            int s = __shfl(sv, j, 16);
            ushort4 v = hb4[(size_t)s * 16 + c];
            ax += bf2f(v.x); ay += bf2f(v.y); az += bf2f(v.z); aw += bf2f(v.w);
        }
    }
    float dv = dis[node];
    ushort4 hv = hb4[(size_t)node * 16 + c];
    float4 bv = (c < 8) ? reinterpret_cast<const float4*>(bmu)[c]
                        : reinterpret_cast<const float4*>(bls)[c - 8];
    float4 o;
    o.x = (ax + bf2f(hv.x)) * dv + bv.x;
    o.y = (ay + bf2f(hv.y)) * dv + bv.y;
    o.z = (az + bf2f(hv.z)) * dv + bv.z;
    o.w = (aw + bf2f(hv.w)) * dv + bv.w;
    if (c < 8) out4[(size_t)node * 8 + c] = o;
    else       out4[(size_t)N_NODES * 8 + (size_t)node * 8 + (c - 8)] = o;
}

extern "C" void kernel_launch(void* const* d_in, const int* in_sizes, int n_in,
                              void* d_out, int out_size, void* d_ws, size_t ws_size,
                              hipStream_t stream) {
    const float* x   = (const float*)d_in[0];
    const float* W1  = (const float*)d_in[1];
    const float* b1  = (const float*)d_in[2];
    const float* Wmu = (const float*)d_in[3];
    const float* bmu = (const float*)d_in[4];
    const float* Wls = (const float*)d_in[5];
    const float* bls = (const float*)d_in[6];
    const int*   ei  = (const int*)d_in[7];
    int E = in_sizes[7] / 2;
    const int* src  = ei;
    const int* dstp = ei + E;

    char* w = (char*)d_ws;
    int* rowoff  = (int*)w;            w += ((size_t)N_NODES + 4) * 4;
    float* dis   = (float*)w;          w += (size_t)N_NODES * 4;
    int* bbase   = (int*)w;            w += ((size_t)NB2 + 4) * 4;
    int* gcur    = (int*)w;            w += ((size_t)NB2 + 4) * 4;
    int* esrc    = (int*)w;            w += (size_t)E * 4;
    unsigned* cpair = (unsigned*)w;    w += (size_t)NB2 * BCAP * 4;
    unsigned short* WbT  = (unsigned short*)w;  w += (size_t)NH * NIN * 2;
    unsigned short* W2T  = (unsigned short*)w;  w += (size_t)NH2 * NH * 2;
    unsigned short* hbuf = (unsigned short*)w;  w += (size_t)N_NODES * NH * 2;
    unsigned short* hid  = (unsigned short*)w;  w += (size_t)N_NODES * NH * 2;
    unsigned short* h23  = (unsigned short*)w;  w += (size_t)N_NODES * NH2 * 2;

    int prep_n = NH * NIN + NH2 * NH;
    k_prep<<<(prep_n + 255) / 256, 256, 0, stream>>>(W1, Wmu, Wls, WbT, W2T, gcur);

    k_coarse<<<NBLK, 256, 0, stream>>>(src, dstp, gcur, cpair, E);
    k_bscan<<<1, 256, 0, stream>>>(gcur, bbase, rowoff);
    k_fine<<<NB2, 256, 0, stream>>>(cpair, gcur, bbase, rowoff, dis, esrc);

    k_gemm1<<<(N_NODES + GBM - 1) / GBM, 256, 0, stream>>>(x, WbT, dis, hbuf, N_NODES);

    k_gather1<<<(N_NODES + 7) / 8, 256, 0, stream>>>(
        (const ushort4*)hbuf, rowoff, esrc, dis, b1, (ushort4*)hid);

    k_gemm2<<<(N_NODES + GBM2 - 1) / GBM2, 256, 0, stream>>>(hid, W2T, dis, h23, N_NODES);

    k_gather2<<<(N_NODES + 15) / 16, 256, 0, stream>>>(
        (const ushort4*)h23, rowoff, esrc, dis, bmu, bls, (float4*)d_out);
}